// Round 1
// baseline (1131.576 us; speedup 1.0000x reference)
//
#include <hip/hip_runtime.h>
#include <math.h>

#define BATCH 16
#define NN 25200
#define NCLS 80
#define K_PRE 1024
#define MAX_DET 300
#define CONF_T 0.4f
#define IOU_T 0.45f

// ---------------------------------------------------------------------------
// Kernel 1: per-anchor score + sortable key.
// key = (float_bits(score) << 32) | (NN-1-n)  -- unique per anchor; descending
// uint64 order == descending score with lower-index-first tie-break, matching
// jax.lax.top_k's stable ordering.
// ---------------------------------------------------------------------------
__global__ void score_kernel(const float* __restrict__ pred,
                             unsigned long long* __restrict__ keys) {
    int idx = blockIdx.x * blockDim.x + threadIdx.x;
    if (idx >= BATCH * NN) return;
    const float* row = pred + (size_t)idx * 85;
    float obj = row[4];
    float best = row[5] * obj;
#pragma unroll 8
    for (int c = 1; c < NCLS; ++c) {
        float v = row[5 + c] * obj;
        best = fmaxf(best, v);
    }
    bool valid = (obj > CONF_T) && (best > CONF_T);
    float score = valid ? best : 0.0f;
    int n = idx % NN;
    keys[idx] = ((unsigned long long)__float_as_uint(score) << 32) |
                (unsigned)(NN - 1 - n);
}

// ---------------------------------------------------------------------------
// Kernel 2: exact top-1024 per batch. 8-round radix select over the 64-bit
// keys (keys are unique -> threshold is exact and selects exactly K_PRE),
// then compact + bitonic sort descending in LDS.
// ---------------------------------------------------------------------------
__global__ void topk_kernel(const unsigned long long* __restrict__ keys,
                            unsigned long long* __restrict__ topkeys) {
    __shared__ unsigned int hist[256];
    __shared__ unsigned long long prefix_sh;
    __shared__ unsigned int k_sh;
    __shared__ unsigned int cnt;
    __shared__ unsigned long long skeys[K_PRE];

    const int b = blockIdx.x, tid = threadIdx.x, nt = blockDim.x;
    const unsigned long long* bk = keys + (size_t)b * NN;

    unsigned long long prefix = 0ull;
    unsigned int k = K_PRE;
    for (int shift = 56; shift >= 0; shift -= 8) {
        hist[tid] = 0u;  // nt == 256
        __syncthreads();
        unsigned long long mask_hi = (shift == 56) ? 0ull : (~0ull << (shift + 8));
        for (int i = tid; i < NN; i += nt) {
            unsigned long long key = bk[i];
            if ((key & mask_hi) == prefix)
                atomicAdd(&hist[(unsigned)((key >> shift) & 0xFFull)], 1u);
        }
        __syncthreads();
        if (tid == 0) {
            unsigned int cum = 0;
            int d;
            for (d = 255; d >= 0; --d) {
                unsigned int c = hist[d];
                if (cum + c >= k) break;
                cum += c;
            }
            if (d < 0) d = 0;
            prefix_sh = prefix | ((unsigned long long)(unsigned)d << shift);
            k_sh = k - cum;
        }
        __syncthreads();
        prefix = prefix_sh;
        k = k_sh;
        __syncthreads();  // protect hist reuse & prefix_sh
    }

    // Compact all keys >= threshold (exactly K_PRE of them).
    if (tid == 0) cnt = 0u;
    for (int i = tid; i < K_PRE; i += nt) skeys[i] = 0ull;
    __syncthreads();
    for (int i = tid; i < NN; i += nt) {
        unsigned long long key = bk[i];
        if (key >= prefix) {
            unsigned p = atomicAdd(&cnt, 1u);
            if (p < K_PRE) skeys[p] = key;
        }
    }
    __syncthreads();

    // Bitonic sort, descending.
    for (unsigned k2 = 2; k2 <= K_PRE; k2 <<= 1) {
        for (unsigned j2 = k2 >> 1; j2 > 0; j2 >>= 1) {
            for (unsigned i = tid; i < K_PRE; i += (unsigned)nt) {
                unsigned ixj = i ^ j2;
                if (ixj > i) {
                    unsigned long long a = skeys[i], c = skeys[ixj];
                    bool desc = ((i & k2) == 0);
                    if (desc ? (a < c) : (a > c)) {
                        skeys[i] = c;
                        skeys[ixj] = a;
                    }
                }
            }
            __syncthreads();
        }
    }

    for (int i = tid; i < K_PRE; i += nt)
        topkeys[(size_t)b * K_PRE + i] = skeys[i];
}

// ---------------------------------------------------------------------------
// Kernel 3: greedy NMS over the sorted 1024, then write the 300x89 output.
// Cross-class IoU is exactly 0 in the reference (class offset 4096 > any box
// extent), so comparing class ids is bit-identical to the offset trick.
// ---------------------------------------------------------------------------
__global__ void __launch_bounds__(K_PRE) nms_kernel(
    const float* __restrict__ pred, const float* __restrict__ conf_logits,
    const float* __restrict__ logits, const float* __restrict__ head,
    const unsigned long long* __restrict__ topkeys, float* __restrict__ out) {
    __shared__ float sx0[K_PRE], sy0[K_PRE], sx1[K_PRE], sy1[K_PRE], sarea[K_PRE];
    __shared__ int scls[K_PRE];
    __shared__ int skeep[K_PRE];
    __shared__ int sscan[K_PRE];

    const int b = blockIdx.x, tid = threadIdx.x;
    unsigned long long key = topkeys[(size_t)b * K_PRE + tid];
    float ts = __uint_as_float((unsigned)(key >> 32));
    int gi = NN - 1 - (int)(key & 0xFFFFFFFFull);

    const float* row = pred + ((size_t)b * NN + gi) * 85;
    float x = row[0], y = row[1], w = row[2], h = row[3], obj = row[4];
    float best = row[5] * obj;
    int bj = 0;
#pragma unroll 8
    for (int c = 1; c < NCLS; ++c) {
        float v = row[5 + c] * obj;
        if (v > best) { best = v; bj = c; }  // first-max == jnp.argmax
    }
    float bx0 = x - w * 0.5f, by0 = y - h * 0.5f;
    float bx1 = x + w * 0.5f, by1 = y + h * 0.5f;
    float area = (bx1 - bx0) * (by1 - by0);

    sx0[tid] = bx0; sy0[tid] = by0; sx1[tid] = bx1; sy1[tid] = by1;
    sarea[tid] = area;
    scls[tid] = bj;
    int mykeep = (ts > 0.0f) ? 1 : 0;
    skeep[tid] = mykeep;
    __syncthreads();

    for (int i = 0; i < K_PRE - 1; ++i) {
        if (skeep[i]) {  // uniform across the block
            if (mykeep && tid > i && scls[i] == bj) {
                float lx = fmaxf(bx0, sx0[i]);
                float ly = fmaxf(by0, sy0[i]);
                float rx = fminf(bx1, sx1[i]);
                float ry = fminf(by1, sy1[i]);
                float iw = fmaxf(rx - lx, 0.0f);
                float ih = fmaxf(ry - ly, 0.0f);
                float inter = iw * ih;
                float iou = inter / (area + sarea[i] - inter + 1e-7f);
                if (iou > IOU_T) { mykeep = 0; skeep[tid] = 0; }
            }
            __syncthreads();
        }
    }

    // Inclusive scan of keep -> output rank (kept rows stay in sorted order,
    // which equals the reference's second top_k; zero rows are already 0).
    sscan[tid] = mykeep;
    __syncthreads();
    for (int off = 1; off < K_PRE; off <<= 1) {
        int v = (tid >= off) ? sscan[tid - off] : 0;
        __syncthreads();
        sscan[tid] += v;
        __syncthreads();
    }
    int rank = sscan[tid] - mykeep;

    if (mykeep && rank < MAX_DET) {
        float* orow = out + ((size_t)b * MAX_DET + rank) * 89;
        orow[0] = bx0; orow[1] = by0; orow[2] = bx1; orow[3] = by1;
        orow[4] = ts;                 // score == conf for valid rows
        orow[5] = (float)bj;
        float cl = conf_logits[((size_t)b * NN + gi) * 5 + 4];
        float obj_sig = 1.0f / (1.0f + expf(-cl));
        const float* lrow = logits + ((size_t)b * NN + gi) * NCLS;
#pragma unroll 4
        for (int c = 0; c < NCLS; ++c) {
            float s = 1.0f / (1.0f + expf(-lrow[c]));
            orow[6 + c] = s * obj_sig;
        }
        orow[86] = obj_sig;
        orow[87] = head[(size_t)b * NN + gi];
        orow[88] = 1.0f;
    }
}

extern "C" void kernel_launch(void* const* d_in, const int* in_sizes, int n_in,
                              void* d_out, int out_size, void* d_ws, size_t ws_size,
                              hipStream_t stream) {
    const float* pred        = (const float*)d_in[0];
    const float* conf_logits = (const float*)d_in[1];
    const float* logits      = (const float*)d_in[2];
    const float* head        = (const float*)d_in[3];
    float* out = (float*)d_out;

    unsigned long long* keys    = (unsigned long long*)d_ws;           // BATCH*NN
    unsigned long long* topkeys = keys + (size_t)BATCH * NN;           // BATCH*K_PRE

    hipMemsetAsync(d_out, 0, (size_t)out_size * sizeof(float), stream);

    int total = BATCH * NN;
    score_kernel<<<(total + 255) / 256, 256, 0, stream>>>(pred, keys);
    topk_kernel<<<BATCH, 256, 0, stream>>>(keys, topkeys);
    nms_kernel<<<BATCH, K_PRE, 0, stream>>>(pred, conf_logits, logits, head,
                                            topkeys, out);
}

// Round 2
// 418.114 us; speedup vs baseline: 2.7064x; 2.7064x over previous
//
#include <hip/hip_runtime.h>
#include <math.h>

#define BATCH 16
#define NN 25200
#define NCLS 80
#define K_PRE 1024
#define MAX_DET 300
#define CONF_T 0.4f
#define IOU_T 0.45f
#define TBIAS 0x3E000000u

// ---------------------------------------------------------------------------
// K1: per-anchor score -> 40-bit sortable key.
// score in {0} U (0.4, 1.0] => bits in {0} U [0x3ECCCCCD, 0x3F800000];
// t = bits - TBIAS fits in 25 bits, monotone. key = t<<15 | (NN-1-n) (unique;
// descending key order == descending score, lower index first on score ties).
// ---------------------------------------------------------------------------
__global__ void score_kernel(const float* __restrict__ pred,
                             unsigned long long* __restrict__ keys) {
    int idx = blockIdx.x * blockDim.x + threadIdx.x;
    if (idx >= BATCH * NN) return;
    const float* row = pred + (size_t)idx * 85;
    float obj = row[4];
    float best = 0.0f;
    if (obj > CONF_T) {
#pragma unroll 16
        for (int c = 0; c < NCLS; ++c) best = fmaxf(best, row[5 + c] * obj);
    }
    unsigned t = (obj > CONF_T && best > CONF_T)
                     ? (__float_as_uint(best) - TBIAS) : 0u;
    int n = idx % NN;
    keys[idx] = ((unsigned long long)t << 15) | (unsigned)(NN - 1 - n);
}

// ---------------------------------------------------------------------------
// K2: exact top-1024 per batch. 4 radix passes (10-bit digits over the 40-bit
// key), parallel suffix-scan digit select, then compact + bitonic sort.
// ---------------------------------------------------------------------------
__global__ void __launch_bounds__(1024) topk_kernel(
    const unsigned long long* __restrict__ keys,
    unsigned long long* __restrict__ topkeys) {
    __shared__ unsigned hist[1024];
    __shared__ unsigned sA[1024], sB[1024];
    __shared__ unsigned long long prefix_sh;
    __shared__ unsigned k_sh, cnt;
    __shared__ unsigned long long skeys[K_PRE];

    const int b = blockIdx.x, tid = threadIdx.x;
    const unsigned long long* bk = keys + (size_t)b * NN;
    unsigned long long prefix = 0ull;
    unsigned k = K_PRE;

    for (int shift = 30; shift >= 0; shift -= 10) {
        hist[tid] = 0u;
        __syncthreads();
        unsigned long long mask_hi =
            (shift == 30) ? 0ull : (~0ull << (shift + 10));
        for (int base = 0; base < 25600; base += 1024) {
            int i = base + tid;
            bool in = (i < NN);
            unsigned long long key = in ? bk[i] : 0ull;
            bool active = in && ((key & mask_hi) == prefix);
            unsigned d = (unsigned)((key >> shift) & 1023u);
            // wave-aggregate the (hot) zero digit, plain atomics otherwise
            bool isz = active && (d == 0u);
            unsigned long long bz = __ballot(isz);
            if (isz &&
                (int)(threadIdx.x & 63u) == (__ffsll((long long)bz) - 1))
                atomicAdd(&hist[0], (unsigned)__popcll(bz));
            if (active && d != 0u) atomicAdd(&hist[d], 1u);
        }
        __syncthreads();
        // suffix-inclusive scan: src[d] = sum_{e>=d} hist[e]
        unsigned* src = sA;
        unsigned* dst = sB;
        src[tid] = hist[tid];
        __syncthreads();
        for (int off = 1; off < 1024; off <<= 1) {
            dst[tid] = src[tid] + ((tid + off < 1024) ? src[tid + off] : 0u);
            __syncthreads();
            unsigned* t2 = src; src = dst; dst = t2;
        }
        unsigned geq = src[tid];
        unsigned gt = (tid < 1023) ? src[tid + 1] : 0u;
        if (gt < k && k <= geq) {
            prefix_sh = prefix | ((unsigned long long)(unsigned)tid << shift);
            k_sh = k - gt;
        }
        __syncthreads();
        prefix = prefix_sh;
        k = k_sh;
        __syncthreads();
    }

    // Compact keys >= threshold (exactly K_PRE of them; keys are unique).
    if (tid == 0) cnt = 0u;
    skeys[tid] = 0ull;
    __syncthreads();
    for (int base = 0; base < 25600; base += 1024) {
        int i = base + tid;
        if (i < NN) {
            unsigned long long key = bk[i];
            if (key >= prefix) {
                unsigned p = atomicAdd(&cnt, 1u);
                if (p < K_PRE) skeys[p] = key;
            }
        }
    }
    __syncthreads();

    // Bitonic sort descending, one element per thread.
    unsigned utid = (unsigned)tid;
    for (unsigned k2 = 2; k2 <= K_PRE; k2 <<= 1) {
        for (unsigned j = k2 >> 1; j > 0; j >>= 1) {
            unsigned ixj = utid ^ j;
            unsigned long long a = skeys[utid], c2 = skeys[ixj];
            unsigned long long mn = (a < c2) ? a : c2;
            unsigned long long mx = (a < c2) ? c2 : a;
            bool desc = ((utid & k2) == 0u);
            bool lower = (utid < ixj);
            unsigned long long mine = desc ? (lower ? mx : mn)
                                           : (lower ? mn : mx);
            __syncthreads();
            skeys[utid] = mine;
            __syncthreads();
        }
    }
    topkeys[(size_t)b * K_PRE + tid] = skeys[tid];
}

// ---------------------------------------------------------------------------
// K3: decode sorted keys -> candidate SoA (box, area, class, score, gi),
// zero the keep flags.
// ---------------------------------------------------------------------------
__global__ void __launch_bounds__(1024) prep_kernel(
    const float* __restrict__ pred,
    const unsigned long long* __restrict__ topkeys,
    float* __restrict__ cx0, float* __restrict__ cy0,
    float* __restrict__ cx1, float* __restrict__ cy1,
    float* __restrict__ carea, float* __restrict__ cscore,
    int* __restrict__ ccls, int* __restrict__ cgi, int* __restrict__ keep) {
    int b = blockIdx.x, tid = threadIdx.x;
    int slot = b * K_PRE + tid;
    unsigned long long key = topkeys[slot];
    unsigned t = (unsigned)(key >> 15);
    int n = NN - 1 - (int)(key & 0x7FFFull);
    keep[slot] = 0;
    cgi[slot] = n;
    if (t == 0u) {
        ccls[slot] = 255;
        cscore[slot] = 0.0f;
        cx0[slot] = 0.0f; cy0[slot] = 0.0f; cx1[slot] = 0.0f; cy1[slot] = 0.0f;
        carea[slot] = 0.0f;
        return;
    }
    const float* row = pred + ((size_t)b * NN + n) * 85;
    float x = row[0], y = row[1], w = row[2], h = row[3], obj = row[4];
    float best = row[5] * obj;
    int bj = 0;
#pragma unroll 16
    for (int c = 1; c < NCLS; ++c) {
        float v = row[5 + c] * obj;
        if (v > best) { best = v; bj = c; }  // first-max == jnp.argmax
    }
    float bx0 = x - w * 0.5f, by0 = y - h * 0.5f;
    float bx1 = x + w * 0.5f, by1 = y + h * 0.5f;
    cx0[slot] = bx0; cy0[slot] = by0; cx1[slot] = bx1; cy1[slot] = by1;
    carea[slot] = (bx1 - bx0) * (by1 - by0);
    cscore[slot] = __uint_as_float(t + TBIAS);  // == top_s bit-exact
    ccls[slot] = bj;
}

// ---------------------------------------------------------------------------
// K4: per-(batch,class) greedy NMS — one wave per class. Cross-class IoU is
// structurally 0 in the reference (4096 class offset), and within a class the
// globally-sorted subsequence greedy == reference's global greedy.
// ---------------------------------------------------------------------------
__global__ void __launch_bounds__(64) nms_kernel(
    const float* __restrict__ cx0, const float* __restrict__ cy0,
    const float* __restrict__ cx1, const float* __restrict__ cy1,
    const float* __restrict__ carea, const int* __restrict__ ccls,
    int* __restrict__ keep) {
    __shared__ int mlist[K_PRE];
    __shared__ float bx0[K_PRE], by0[K_PRE], bx1[K_PRE], by1[K_PRE],
        bar[K_PRE];
    __shared__ unsigned char kf[K_PRE];

    int b = blockIdx.x / NCLS, c = blockIdx.x % NCLS;
    int lane = threadIdx.x;
    int base = b * K_PRE;

    // Gather class members in sorted order via ballot compaction.
    int m = 0;
    for (int w = 0; w < K_PRE / 64; ++w) {
        int i = w * 64 + lane;
        bool my = (ccls[base + i] == c);
        unsigned long long bal = __ballot(my);
        if (my) {
            int pos = __popcll(bal & ((1ull << lane) - 1ull));
            mlist[m + pos] = i;
        }
        m += __popcll(bal);
    }
    for (int j = lane; j < m; j += 64) {
        int i = mlist[j];
        bx0[j] = cx0[base + i]; by0[j] = cy0[base + i];
        bx1[j] = cx1[base + i]; by1[j] = cy1[base + i];
        bar[j] = carea[base + i];
        kf[j] = 1;
    }
    __syncthreads();

    for (int i = 0; i < m; ++i) {
        if (kf[i]) {
            float ax0 = bx0[i], ay0 = by0[i], ax1 = bx1[i], ay1 = by1[i];
            float aa = bar[i];
            for (int j = i + 1 + lane; j < m; j += 64) {
                if (kf[j]) {
                    float lx = fmaxf(ax0, bx0[j]);
                    float ly = fmaxf(ay0, by0[j]);
                    float rx = fminf(ax1, bx1[j]);
                    float ry = fminf(ay1, by1[j]);
                    float iw = fmaxf(rx - lx, 0.0f);
                    float ih = fmaxf(ry - ly, 0.0f);
                    float inter = iw * ih;
                    float iou = inter / (aa + bar[j] - inter + 1e-7f);
                    if (iou > IOU_T) kf[j] = 0;
                }
            }
        }
        __syncthreads();
    }
    for (int j = lane; j < m; j += 64)
        if (kf[j]) keep[base + mlist[j]] = 1;
}

// ---------------------------------------------------------------------------
// K5: rank kept rows (prefix scan) and write the 300x89 output rows.
// ---------------------------------------------------------------------------
__global__ void __launch_bounds__(1024) output_kernel(
    const float* __restrict__ conf_logits, const float* __restrict__ logits,
    const float* __restrict__ head, const float* __restrict__ cx0,
    const float* __restrict__ cy0, const float* __restrict__ cx1,
    const float* __restrict__ cy1, const float* __restrict__ cscore,
    const int* __restrict__ ccls, const int* __restrict__ cgi,
    const int* __restrict__ keep, float* __restrict__ out) {
    __shared__ unsigned sA[1024], sB[1024];
    int b = blockIdx.x, tid = threadIdx.x;
    int slot = b * K_PRE + tid;
    int kp = keep[slot];
    unsigned* src = sA;
    unsigned* dst = sB;
    src[tid] = (unsigned)kp;
    __syncthreads();
    for (int off = 1; off < 1024; off <<= 1) {
        dst[tid] = src[tid] + ((tid >= off) ? src[tid - off] : 0u);
        __syncthreads();
        unsigned* t2 = src; src = dst; dst = t2;
    }
    int rank = (int)src[tid] - kp;

    if (kp && rank < MAX_DET) {
        int gi = cgi[slot];
        float* orow = out + ((size_t)b * MAX_DET + rank) * 89;
        orow[0] = cx0[slot]; orow[1] = cy0[slot];
        orow[2] = cx1[slot]; orow[3] = cy1[slot];
        orow[4] = cscore[slot];
        orow[5] = (float)ccls[slot];
        float cl = conf_logits[((size_t)b * NN + gi) * 5 + 4];
        float obj_sig = 1.0f / (1.0f + expf(-cl));
        const float* lrow = logits + ((size_t)b * NN + gi) * NCLS;
#pragma unroll 8
        for (int c = 0; c < NCLS; ++c) {
            float s = 1.0f / (1.0f + expf(-lrow[c]));
            orow[6 + c] = s * obj_sig;
        }
        orow[86] = obj_sig;
        orow[87] = head[(size_t)b * NN + gi];
        orow[88] = 1.0f;
    }
}

extern "C" void kernel_launch(void* const* d_in, const int* in_sizes, int n_in,
                              void* d_out, int out_size, void* d_ws,
                              size_t ws_size, hipStream_t stream) {
    const float* pred        = (const float*)d_in[0];
    const float* conf_logits = (const float*)d_in[1];
    const float* logits      = (const float*)d_in[2];
    const float* head        = (const float*)d_in[3];
    float* out = (float*)d_out;

    char* ws = (char*)d_ws;
    unsigned long long* keys = (unsigned long long*)ws;                // 3,225,600 B
    unsigned long long* topkeys =
        (unsigned long long*)(ws + (size_t)BATCH * NN * 8);            // 131,072 B
    // Candidate SoA aliases the keys region (keys are dead after topk_kernel).
    const size_t S = (size_t)BATCH * K_PRE * 4;  // 65,536 B per array
    float* cx0    = (float*)(ws + 0 * S);
    float* cy0    = (float*)(ws + 1 * S);
    float* cx1    = (float*)(ws + 2 * S);
    float* cy1    = (float*)(ws + 3 * S);
    float* carea  = (float*)(ws + 4 * S);
    float* cscore = (float*)(ws + 5 * S);
    int*   ccls   = (int*)(ws + 6 * S);
    int*   cgi    = (int*)(ws + 7 * S);
    int*   keep   = (int*)(ws + 8 * S);

    hipMemsetAsync(d_out, 0, (size_t)out_size * sizeof(float), stream);

    int total = BATCH * NN;
    score_kernel<<<(total + 255) / 256, 256, 0, stream>>>(pred, keys);
    topk_kernel<<<BATCH, 1024, 0, stream>>>(keys, topkeys);
    prep_kernel<<<BATCH, 1024, 0, stream>>>(pred, topkeys, cx0, cy0, cx1, cy1,
                                            carea, cscore, ccls, cgi, keep);
    nms_kernel<<<BATCH * NCLS, 64, 0, stream>>>(cx0, cy0, cx1, cy1, carea,
                                                ccls, keep);
    output_kernel<<<BATCH, 1024, 0, stream>>>(conf_logits, logits, head, cx0,
                                              cy0, cx1, cy1, cscore, ccls,
                                              cgi, keep, out);
}

// Round 3
// 334.549 us; speedup vs baseline: 3.3824x; 1.2498x over previous
//
#include <hip/hip_runtime.h>
#include <math.h>

#define BATCH 16
#define NN 25200
#define NCLS 80
#define K_PRE 1024
#define MAX_DET 300
#define CONF_T 0.4f
#define IOU_T 0.45f
#define TBIAS 0x3E000000u
// key layout (47 bits): t(25) << 22 | (NN-1-n)(15) << 7 | cls(7)
// (t, n) is unique, so cls in the low bits never affects sort order.
#define RROWS 128
#define STHREADS 512
#define CAND_STRIDE 50400  // floats per batch = 201,600 B (== batch keys size)

// ---------------------------------------------------------------------------
// K1: LDS-staged score + argmax + pass-1 radix histogram.
// ---------------------------------------------------------------------------
__global__ void __launch_bounds__(STHREADS) score_kernel(
    const float* __restrict__ pred, unsigned long long* __restrict__ keys,
    unsigned* __restrict__ ghist) {
    __shared__ float srow[RROWS * 85];
    __shared__ unsigned lh[1024];

    const int tile = blockIdx.x, b = blockIdx.y, tid = threadIdx.x;
    const int row0 = tile * RROWS;
    int nrows = NN - row0;
    if (nrows > RROWS) nrows = RROWS;

    const float4* g4 = (const float4*)(pred + ((size_t)b * NN + row0) * 85);
    float4* l4 = (float4*)srow;
    const int nf4 = (nrows * 85) >> 2;  // nrows % 4 == 0 always
    for (int i = tid; i < nf4; i += STHREADS) l4[i] = g4[i];
    lh[tid] = 0u;
    lh[tid + STHREADS] = 0u;
    __syncthreads();

    const int r = tid >> 2, sub = tid & 3;
    float best = 0.0f;
    int bc = sub * 20;
    float obj = 0.0f;
    if (r < nrows) {
        obj = srow[r * 85 + 4];
        if (obj > CONF_T) {
            const float* cp = &srow[r * 85 + 5 + sub * 20];
#pragma unroll
            for (int i = 0; i < 20; ++i) {
                float v = cp[i] * obj;
                if (v > best) { best = v; bc = sub * 20 + i; }  // first-max
            }
        }
    }
    // reduce (best, bc) across the 4 lanes of this row, first-max semantics
#pragma unroll
    for (int d = 1; d < 4; d <<= 1) {
        float ov = __shfl_xor(best, d);
        int oc = __shfl_xor(bc, d);
        if (ov > best || (ov == best && oc < bc)) { best = ov; bc = oc; }
    }
    if (r < nrows && sub == 0) {
        unsigned t = (obj > CONF_T && best > CONF_T)
                         ? (__float_as_uint(best) - TBIAS) : 0u;
        int n = row0 + r;
        keys[(size_t)b * NN + n] =
            ((unsigned long long)t << 22) |
            ((unsigned long long)(unsigned)(NN - 1 - n) << 7) | (unsigned)bc;
        if (t) atomicAdd(&lh[t >> 15], 1u);
    }
    __syncthreads();
    for (int i = tid; i < 1024; i += STHREADS) {
        unsigned v = lh[i];
        if (v) atomicAdd(&ghist[b * 1024 + i], v);
    }
}

// ---------------------------------------------------------------------------
// K2: exact top-1024 via 1-pass digit select (hist precomputed) + compact +
// bitonic-2048 sort, with prep fused at the tail. Candidate SoA overlays this
// batch's own (dead) keys region.
// ---------------------------------------------------------------------------
__global__ void __launch_bounds__(1024) topk_kernel(
    const unsigned long long* __restrict__ keys,
    const unsigned* __restrict__ ghist, const float* __restrict__ pred,
    float* __restrict__ ws_f) {
    __shared__ unsigned sA[1024], sB[1024];
    __shared__ unsigned long long skeys[2048];
    __shared__ unsigned sel_d0, sel_cnt;

    const int b = blockIdx.x, tid = threadIdx.x;
    const unsigned long long* bk = keys + (size_t)b * NN;

    // suffix-inclusive scan of the 10-bit digit histogram
    unsigned* src = sA;
    unsigned* dst = sB;
    src[tid] = ghist[b * 1024 + tid];
    __syncthreads();
    for (int off = 1; off < 1024; off <<= 1) {
        dst[tid] = src[tid] + ((tid + off < 1024) ? src[tid + off] : 0u);
        __syncthreads();
        unsigned* t2 = src; src = dst; dst = t2;
    }
    unsigned total = src[0];
    unsigned K = total < 1024u ? total : 1024u;
    if (tid == 0) { sel_d0 = 0u; sel_cnt = 0u; }
    skeys[tid] = 0ull;
    skeys[tid + 1024] = 0ull;
    __syncthreads();
    if (total) {
        unsigned geq = src[tid];
        unsigned gt = (tid < 1023) ? src[tid + 1] : 0u;
        if (gt < K && K <= geq) sel_d0 = (unsigned)tid;  // unique writer
    }
    __syncthreads();
    const unsigned d0 = sel_d0;

    // compact all valid keys with digit >= d0 (~K + one bucket, << 2048)
    for (int base = 0; base < 25600; base += 1024) {
        int i = base + tid;
        if (i < NN) {
            unsigned long long key = bk[i];
            unsigned t = (unsigned)(key >> 22);
            if (t && (t >> 15) >= d0) {
                unsigned p = atomicAdd(&sel_cnt, 1u);
                if (p < 2048u) skeys[p] = key;
            }
        }
    }
    __syncthreads();

    // bitonic sort 2048 descending; thread owns pair (i, i|j)
    for (unsigned k2 = 2; k2 <= 2048; k2 <<= 1) {
        for (unsigned j = k2 >> 1; j > 0; j >>= 1) {
            unsigned i = ((tid & ~(j - 1)) << 1) | (tid & (j - 1));
            unsigned ixj = i | j;
            unsigned long long a = skeys[i], c = skeys[ixj];
            bool desc = ((i & k2) == 0u);
            if (desc ? (a < c) : (a > c)) { skeys[i] = c; skeys[ixj] = a; }
            __syncthreads();
        }
    }

    // fused prep: decode slot tid, gather box, write candidate SoA
    unsigned long long key = skeys[tid];
    unsigned t = (unsigned)(key >> 22);
    int n = NN - 1 - (int)((key >> 7) & 32767u);
    float* cbase = ws_f + (size_t)b * CAND_STRIDE;
    float* cx0 = cbase;
    float* cy0 = cbase + 1024;
    float* cx1 = cbase + 2048;
    float* cy1 = cbase + 3072;
    float* carea = cbase + 4096;
    float* cscore = cbase + 5120;
    int* ccls = (int*)(cbase + 6144);
    int* cgi = (int*)(cbase + 7168);
    int* keep = (int*)(cbase + 8192);
    keep[tid] = 0;
    cgi[tid] = n;
    if (t == 0u) {
        ccls[tid] = 255;
    } else {
        const float* row = pred + ((size_t)b * NN + n) * 85;
        float x = row[0], y = row[1], w = row[2], h = row[3];
        float bx0 = x - w * 0.5f, by0 = y - h * 0.5f;
        float bx1 = x + w * 0.5f, by1 = y + h * 0.5f;
        cx0[tid] = bx0; cy0[tid] = by0; cx1[tid] = bx1; cy1[tid] = by1;
        carea[tid] = (bx1 - bx0) * (by1 - by0);
        cscore[tid] = __uint_as_float(t + TBIAS);  // bit-exact top_s
        ccls[tid] = (int)(key & 127u);
    }
}

// ---------------------------------------------------------------------------
// K3: per-(batch,class) greedy NMS — one wave per class.
// ---------------------------------------------------------------------------
__global__ void __launch_bounds__(64) nms_kernel(float* __restrict__ ws_f) {
    __shared__ int mlist[K_PRE];
    __shared__ float bx0[K_PRE], by0[K_PRE], bx1[K_PRE], by1[K_PRE],
        bar[K_PRE];
    __shared__ unsigned char kf[K_PRE];

    const int b = blockIdx.x / NCLS, c = blockIdx.x % NCLS;
    const int lane = threadIdx.x;
    float* cbase = ws_f + (size_t)b * CAND_STRIDE;
    const float* cx0 = cbase;
    const float* cy0 = cbase + 1024;
    const float* cx1 = cbase + 2048;
    const float* cy1 = cbase + 3072;
    const float* carea = cbase + 4096;
    const int* ccls = (const int*)(cbase + 6144);
    int* keep = (int*)(cbase + 8192);

    int m = 0;
    for (int w = 0; w < K_PRE / 64; ++w) {
        int i = w * 64 + lane;
        bool my = (ccls[i] == c);
        unsigned long long bal = __ballot(my);
        if (my) {
            int pos = __popcll(bal & ((1ull << lane) - 1ull));
            mlist[m + pos] = i;
        }
        m += __popcll(bal);
    }
    for (int j = lane; j < m; j += 64) {
        int i = mlist[j];
        bx0[j] = cx0[i]; by0[j] = cy0[i];
        bx1[j] = cx1[i]; by1[j] = cy1[i];
        bar[j] = carea[i];
        kf[j] = 1;
    }
    __syncthreads();

    for (int i = 0; i < m; ++i) {
        if (kf[i]) {
            float ax0 = bx0[i], ay0 = by0[i], ax1 = bx1[i], ay1 = by1[i];
            float aa = bar[i];
            for (int j = i + 1 + lane; j < m; j += 64) {
                if (kf[j]) {
                    float lx = fmaxf(ax0, bx0[j]);
                    float ly = fmaxf(ay0, by0[j]);
                    float rx = fminf(ax1, bx1[j]);
                    float ry = fminf(ay1, by1[j]);
                    float iw = fmaxf(rx - lx, 0.0f);
                    float ih = fmaxf(ry - ly, 0.0f);
                    float inter = iw * ih;
                    float iou = inter / (aa + bar[j] - inter + 1e-7f);
                    if (iou > IOU_T) kf[j] = 0;
                }
            }
        }
        __syncthreads();
    }
    for (int j = lane; j < m; j += 64)
        if (kf[j]) keep[mlist[j]] = 1;
}

// ---------------------------------------------------------------------------
// K4: rank kept rows (prefix scan) and write the 300x89 output rows.
// ---------------------------------------------------------------------------
__global__ void __launch_bounds__(1024) output_kernel(
    const float* __restrict__ conf_logits, const float* __restrict__ logits,
    const float* __restrict__ head, const float* __restrict__ ws_f,
    float* __restrict__ out) {
    __shared__ unsigned sA[1024], sB[1024];
    const int b = blockIdx.x, tid = threadIdx.x;
    const float* cbase = ws_f + (size_t)b * CAND_STRIDE;
    const float* cx0 = cbase;
    const float* cy0 = cbase + 1024;
    const float* cx1 = cbase + 2048;
    const float* cy1 = cbase + 3072;
    const float* cscore = cbase + 5120;
    const int* ccls = (const int*)(cbase + 6144);
    const int* cgi = (const int*)(cbase + 7168);
    const int* keep = (const int*)(cbase + 8192);

    int kp = keep[tid];
    unsigned* src = sA;
    unsigned* dst = sB;
    src[tid] = (unsigned)kp;
    __syncthreads();
    for (int off = 1; off < 1024; off <<= 1) {
        dst[tid] = src[tid] + ((tid >= off) ? src[tid - off] : 0u);
        __syncthreads();
        unsigned* t2 = src; src = dst; dst = t2;
    }
    int rank = (int)src[tid] - kp;

    if (kp && rank < MAX_DET) {
        int gi = cgi[tid];
        float* orow = out + ((size_t)b * MAX_DET + rank) * 89;
        orow[0] = cx0[tid]; orow[1] = cy0[tid];
        orow[2] = cx1[tid]; orow[3] = cy1[tid];
        orow[4] = cscore[tid];
        orow[5] = (float)ccls[tid];
        float cl = conf_logits[((size_t)b * NN + gi) * 5 + 4];
        float obj_sig = 1.0f / (1.0f + expf(-cl));
        // logits row is 80 floats = 320 B, always 16B-aligned
        const float4* lrow4 =
            (const float4*)(logits + ((size_t)b * NN + gi) * NCLS);
#pragma unroll 4
        for (int q = 0; q < 20; ++q) {
            float4 l4 = lrow4[q];
            orow[6 + 4 * q + 0] = obj_sig / (1.0f + expf(-l4.x));
            orow[6 + 4 * q + 1] = obj_sig / (1.0f + expf(-l4.y));
            orow[6 + 4 * q + 2] = obj_sig / (1.0f + expf(-l4.z));
            orow[6 + 4 * q + 3] = obj_sig / (1.0f + expf(-l4.w));
        }
        orow[86] = obj_sig;
        orow[87] = head[(size_t)b * NN + gi];
        orow[88] = 1.0f;
    }
}

extern "C" void kernel_launch(void* const* d_in, const int* in_sizes, int n_in,
                              void* d_out, int out_size, void* d_ws,
                              size_t ws_size, hipStream_t stream) {
    const float* pred        = (const float*)d_in[0];
    const float* conf_logits = (const float*)d_in[1];
    const float* logits      = (const float*)d_in[2];
    const float* head        = (const float*)d_in[3];
    float* out = (float*)d_out;

    char* ws = (char*)d_ws;
    unsigned long long* keys = (unsigned long long*)ws;  // 16*25200*8 = 3,225,600 B
    unsigned* ghist = (unsigned*)(ws + (size_t)BATCH * NN * 8);  // 65,536 B
    float* ws_f = (float*)ws;  // cand SoA overlays each batch's own keys

    hipMemsetAsync(d_out, 0, (size_t)out_size * sizeof(float), stream);
    hipMemsetAsync(ghist, 0, (size_t)BATCH * 1024 * sizeof(unsigned), stream);

    dim3 sgrid((NN + RROWS - 1) / RROWS, BATCH);
    score_kernel<<<sgrid, STHREADS, 0, stream>>>(pred, keys, ghist);
    topk_kernel<<<BATCH, 1024, 0, stream>>>(keys, ghist, pred, ws_f);
    nms_kernel<<<BATCH * NCLS, 64, 0, stream>>>(ws_f);
    output_kernel<<<BATCH, 1024, 0, stream>>>(conf_logits, logits, head, ws_f,
                                              out);
}